// Round 14
// baseline (418.413 us; speedup 1.0000x reference)
//
#include <hip/hip_runtime.h>

#define NN   50000
#define E0   800000
#define ET   850000
#define FIN  166
#define KP1  192
#define HID  64
#define NH   8
#define F1   512
#define SCHUNK 52
#define DEGPAD (1024*SCHUNK)
#define G1BX 391
#define G1BLK (G1BX*4)
#define SCB  832

typedef __attribute__((ext_vector_type(8))) short short8;
typedef __attribute__((ext_vector_type(4))) float f32x4;
typedef __attribute__((ext_vector_type(4))) int int4v;
typedef unsigned short ush;

__device__ __forceinline__ float bf2f(unsigned short u){
  unsigned int x = ((unsigned int)u) << 16;
  return __builtin_bit_cast(float, x);
}
__device__ __forceinline__ unsigned short f2bf(float f){
  unsigned int x = __builtin_bit_cast(unsigned int, f);
  x += 0x7FFFu + ((x >> 16) & 1u);
  return (unsigned short)(x >> 16);
}

// ---- fused prep (8-wide): pad/convert x, transpose W1,W2,Wc1, histogram ----
#define G1 (KP1/8)
#define T0V (NN*G1)
#define T1V (T0V + 512*G1)
#define T2V (T1V + 64*64)
#define T2W (T2V + 512)
#define T3V (T2W + ET)
__global__ __launch_bounds__(256) void k_prep_v(const float* __restrict__ x,
                                                const float* __restrict__ W1,
                                                const float* __restrict__ W2,
                                                const float* __restrict__ Wc1,
                                                const int* __restrict__ ei,
                                                ush* __restrict__ xpad,
                                                ush* __restrict__ W1t,
                                                ush* __restrict__ W2t,
                                                ush* __restrict__ Wc1t,
                                                int* __restrict__ deg){
  int i = blockIdx.x*256 + threadIdx.x;
  if (i >= T3V) return;
  if (i < T0V){
    int n = i / G1, g = i - n*G1, k0 = g*8;
    short8 o;
    #pragma unroll
    for (int j = 0; j < 8; j++){
      int k = k0 + j;
      o[j] = (short)f2bf(k < FIN ? x[(size_t)n*FIN + k] : 0.f);
    }
    *(short8*)(xpad + (size_t)n*KP1 + k0) = o;
  } else if (i < T1V){
    int j = i - T0V;
    int col = j / G1, g = j - col*G1, k0 = g*8;
    short8 o;
    #pragma unroll
    for (int q = 0; q < 8; q++){
      int k = k0 + q;
      o[q] = (short)f2bf(k < FIN ? W1[(size_t)k*512 + col] : 0.f);
    }
    *(short8*)(W1t + (size_t)col*KP1 + k0) = o;
  } else if (i < T2V){
    int j = i - T1V;
    int col = j >> 6, g = j & 63, k0 = g*8;
    short8 o;
    #pragma unroll
    for (int q = 0; q < 8; q++)
      o[q] = (short)f2bf(W2[(size_t)(k0 + q)*HID + col]);
    *(short8*)(W2t + (size_t)col*F1 + k0) = o;
  } else if (i < T2W){
    int j = i - T2V;
    int col = j >> 3, k0 = (j & 7)*8;
    short8 o;
    #pragma unroll
    for (int q = 0; q < 8; q++)
      o[q] = (short)f2bf(Wc1[(size_t)(k0 + q)*HID + col]);
    *(short8*)(Wc1t + (size_t)col*HID + k0) = o;
  } else {
    int e = i - T2W;
    int dst = (e < E0) ? ei[E0 + e] : (e - E0);
    atomicAdd(&deg[dst], 1);
  }
}

// ---- exclusive scan of deg -> offs[NN+1]; also zeroes cur ----
__global__ __launch_bounds__(1024) void k_scan(const int* __restrict__ deg,
                                               int* __restrict__ offs,
                                               int* __restrict__ cur){
  __shared__ int sums[1024];
  int t = threadIdx.x;
  for (int i = t; i < NN; i += 1024) cur[i] = 0;
  int base = t * SCHUNK;
  int4v v[13];
  int loc = 0;
  #pragma unroll
  for (int c = 0; c < 13; c++){
    v[c] = *(const int4v*)(deg + base + c*4);
    loc += v[c].x + v[c].y + v[c].z + v[c].w;
  }
  sums[t] = loc; __syncthreads();
  for (int off = 1; off < 1024; off <<= 1){
    int s = (t >= off) ? sums[t - off] : 0;
    __syncthreads();
    sums[t] += s;
    __syncthreads();
  }
  int run = sums[t] - loc;
  #pragma unroll
  for (int c = 0; c < 13; c++){
    int i0 = base + c*4;
    if (i0 + 0 < NN) offs[i0 + 0] = run;  run += v[c].x;
    if (i0 + 1 < NN) offs[i0 + 1] = run;  run += v[c].y;
    if (i0 + 2 < NN) offs[i0 + 2] = run;  run += v[c].z;
    if (i0 + 3 < NN) offs[i0 + 3] = run;  run += v[c].w;
  }
  if (t == 1023) offs[NN] = sums[1023];
}

// ---- FUSED: scatter (last SCB blocks) + GEMM1 (first G1BLK blocks) ----
__global__ __launch_bounds__(256) void k_sg1(const int* __restrict__ ei,
                                             const int* __restrict__ offs,
                                             int* __restrict__ cur,
                                             int* __restrict__ esrc,
                                             const ush* __restrict__ xpad,
                                             const ush* __restrict__ W1t,
                                             const float* __restrict__ a_s,
                                             const float* __restrict__ a_d,
                                             ush* __restrict__ xp1,
                                             float* __restrict__ als,
                                             float* __restrict__ ald){
  __shared__ ush Bs[128][200];
  const int bid = blockIdx.x;
  if (bid >= G1BLK){
    int vb = bid - G1BLK;
    for (int e = vb*256 + (int)threadIdx.x; e < ET; e += SCB*256){
      int src, dst;
      if (e < E0){ src = ei[e]; dst = ei[E0 + e]; }
      else       { src = e - E0; dst = src; }
      int pos = offs[dst] + atomicAdd(&cur[dst], 1);
      esrc[pos] = src;
    }
    return;
  }
  const int m0 = (bid % G1BX)*128, n0 = (bid / G1BX)*128;
  const int t = threadIdx.x, wid = t>>6, l = t&63;
  const int wr = wid>>1, wc = wid&1;
  const int lr = l&15, ksl = (l>>4)*8;
  const int srow = t>>1, sc = (t&1)*16;

  {
    const ush* Bp = W1t + (size_t)(n0 + srow)*KP1;
    #pragma unroll
    for (int c = 0; c < 6; c++){
      short8 b0 = *(const short8*)(Bp + c*32 + sc);
      short8 b1 = *(const short8*)(Bp + c*32 + sc + 8);
      *(short8*)&Bs[srow][c*32 + sc]     = b0;
      *(short8*)&Bs[srow][c*32 + sc + 8] = b1;
    }
  }
  __syncthreads();

  f32x4 acc[4][4];
  #pragma unroll
  for (int m = 0; m < 4; m++)
    #pragma unroll
    for (int n = 0; n < 4; n++)
      #pragma unroll
      for (int j = 0; j < 4; j++) acc[m][n][j] = 0.f;

  int arow[4];
  #pragma unroll
  for (int m = 0; m < 4; m++){
    int r = m0 + wr*64 + m*16 + lr;
    arow[m] = r < NN ? r : NN-1;
  }

  for (int s = 0; s < 6; s++){
    const int kk = s*32;
    short8 af[4], bfr[4];
    #pragma unroll
    for (int m = 0; m < 4; m++)
      af[m] = *(const short8*)(xpad + (size_t)arow[m]*KP1 + kk + ksl);
    #pragma unroll
    for (int n = 0; n < 4; n++)
      bfr[n] = *(const short8*)&Bs[wc*64 + n*16 + lr][kk + ksl];
    #pragma unroll
    for (int m = 0; m < 4; m++)
      #pragma unroll
      for (int n = 0; n < 4; n++)
        acc[m][n] = __builtin_amdgcn_mfma_f32_16x16x32_bf16(af[m], bfr[n], acc[m][n], 0, 0, 0);
  }

  #pragma unroll
  for (int m = 0; m < 4; m++)
    #pragma unroll
    for (int n = 0; n < 4; n++)
      #pragma unroll
      for (int j = 0; j < 4; j++){
        int row = m0 + wr*64 + m*16 + (l>>4)*4 + j;
        int col = n0 + wc*64 + n*16 + lr;
        if (row < NN) xp1[(size_t)row*F1 + col] = f2bf(acc[m][n][j]);
      }

  const int head = (bid / G1BX)*2 + wc;
  float asv[4], adv[4];
  #pragma unroll
  for (int n = 0; n < 4; n++){
    asv[n] = a_s[head*64 + n*16 + lr];
    adv[n] = a_d[head*64 + n*16 + lr];
  }
  #pragma unroll
  for (int m = 0; m < 4; m++)
    #pragma unroll
    for (int j = 0; j < 4; j++){
      float ps = 0.f, pd = 0.f;
      #pragma unroll
      for (int n = 0; n < 4; n++){
        ps = fmaf(acc[m][n][j], asv[n], ps);
        pd = fmaf(acc[m][n][j], adv[n], pd);
      }
      #pragma unroll
      for (int o = 1; o < 16; o <<= 1){
        ps += __shfl_xor(ps, o, 64);
        pd += __shfl_xor(pd, o, 64);
      }
      if (lr == 0){
        int row = m0 + wr*64 + m*16 + (l>>4)*4 + j;
        if (row < NN){
          als[(size_t)row*NH + head] = fminf(fmaxf(ps, -30.f), 30.f);
          ald[(size_t)row*NH + head] = fminf(fmaxf(pd, -30.f), 30.f);
        }
      }
    }
}

// ---- GEMM2: full-B in LDS once; A direct global; no k-loop barriers ----
__global__ __launch_bounds__(256) void k_gemm2(const ush* __restrict__ h1,
                                               const ush* __restrict__ W2t,
                                               const float* __restrict__ a_s,
                                               const float* __restrict__ a_d,
                                               ush* __restrict__ xp2,
                                               float* __restrict__ als,
                                               float* __restrict__ ald){
  __shared__ ush Bs[64][520];
  const int m0 = blockIdx.x*128;
  const int t = threadIdx.x, wid = t>>6, l = t&63;
  const int lr = l&15, ksl = (l>>4)*8;

  {
    const int br = t>>2, bq = (t&3)*128;
    const ush* Bp = W2t + (size_t)br*F1 + bq;
    #pragma unroll
    for (int c = 0; c < 16; c++){
      short8 b = *(const short8*)(Bp + c*8);
      *(short8*)&Bs[br][bq + c*8] = b;
    }
  }
  __syncthreads();

  f32x4 acc[2][4];
  #pragma unroll
  for (int m = 0; m < 2; m++)
    #pragma unroll
    for (int n = 0; n < 4; n++)
      #pragma unroll
      for (int j = 0; j < 4; j++) acc[m][n][j] = 0.f;

  int arow[2];
  #pragma unroll
  for (int m = 0; m < 2; m++){
    int r = m0 + wid*32 + m*16 + lr;
    arow[m] = r < NN ? r : NN-1;
  }

  for (int s = 0; s < 16; s++){
    const int kk = s*32;
    short8 af[2], bfr[4];
    #pragma unroll
    for (int m = 0; m < 2; m++)
      af[m] = *(const short8*)(h1 + (size_t)arow[m]*F1 + kk + ksl);
    #pragma unroll
    for (int n = 0; n < 4; n++)
      bfr[n] = *(const short8*)&Bs[n*16 + lr][kk + ksl];
    #pragma unroll
    for (int m = 0; m < 2; m++)
      #pragma unroll
      for (int n = 0; n < 4; n++)
        acc[m][n] = __builtin_amdgcn_mfma_f32_16x16x32_bf16(af[m], bfr[n], acc[m][n], 0, 0, 0);
  }

  #pragma unroll
  for (int m = 0; m < 2; m++)
    #pragma unroll
    for (int n = 0; n < 4; n++)
      #pragma unroll
      for (int j = 0; j < 4; j++){
        int row = m0 + wid*32 + m*16 + (l>>4)*4 + j;
        int col = n*16 + lr;
        if (row < NN) xp2[(size_t)row*HID + col] = f2bf(acc[m][n][j]);
      }

  float asv[4], adv[4];
  #pragma unroll
  for (int n = 0; n < 4; n++){
    asv[n] = a_s[n*16 + lr];
    adv[n] = a_d[n*16 + lr];
  }
  #pragma unroll
  for (int m = 0; m < 2; m++)
    #pragma unroll
    for (int j = 0; j < 4; j++){
      float ps = 0.f, pd = 0.f;
      #pragma unroll
      for (int n = 0; n < 4; n++){
        ps = fmaf(acc[m][n][j], asv[n], ps);
        pd = fmaf(acc[m][n][j], adv[n], pd);
      }
      #pragma unroll
      for (int o = 1; o < 16; o <<= 1){
        ps += __shfl_xor(ps, o, 64);
        pd += __shfl_xor(pd, o, 64);
      }
      if (lr == 0){
        int row = m0 + wid*32 + m*16 + (l>>4)*4 + j;
        if (row < NN){
          als[row] = fminf(fmaxf(ps, -30.f), 30.f);
          ald[row] = fminf(fmaxf(pd, -30.f), 30.f);
        }
      }
    }
}

// ---- layer-1 aggregation: wave per dst; node-range split (diagnostic) ----
__global__ __launch_bounds__(256) void k_agg1(const int* __restrict__ offs,
                                              const int* __restrict__ esrc,
                                              const ush* __restrict__ xp1,
                                              const float* __restrict__ als,
                                              const float* __restrict__ ald,
                                              const float* __restrict__ b1,
                                              ush* __restrict__ h1,
                                              int nodeBase, int nodeCnt){
  int w = (blockIdx.x*256 + threadIdx.x) >> 6;
  int l = threadIdx.x & 63;
  if (w >= nodeCnt) return;
  w += nodeBase;
  int h = l >> 3;
  int f0 = l * 8;
  float ad = ald[w*NH + h];
  int s0 = offs[w], s1 = offs[w+1];
  float accA[8], accB[8];
  #pragma unroll
  for (int j = 0; j < 8; j++){ accA[j] = 0.f; accB[j] = 0.f; }
  float den = 0.f;

  for (int base = s0; base < s1; base += 64){
    int cnt = min(64, s1 - base);
    int myE = (base + l < s1) ? esrc[base + l] : 0;
    int j = 0;
    for (; j + 4 <= cnt; j += 4){
      int sA = __shfl(myE, j,   64);
      int sB = __shfl(myE, j+1, 64);
      int sC = __shfl(myE, j+2, 64);
      int sD = __shfl(myE, j+3, 64);
      float eA = als[sA*NH + h] + ad;
      float eB = als[sB*NH + h] + ad;
      float eC = als[sC*NH + h] + ad;
      float eD = als[sD*NH + h] + ad;
      eA = fmaxf(eA, 0.2f*eA); eB = fmaxf(eB, 0.2f*eB);
      eC = fmaxf(eC, 0.2f*eC); eD = fmaxf(eD, 0.2f*eD);
      float wA = __expf(eA), wB = __expf(eB), wC = __expf(eC), wD = __expf(eD);
      short8 vA = *(const short8*)(xp1 + (size_t)sA*F1 + f0);
      short8 vB = *(const short8*)(xp1 + (size_t)sB*F1 + f0);
      short8 vC = *(const short8*)(xp1 + (size_t)sC*F1 + f0);
      short8 vD = *(const short8*)(xp1 + (size_t)sD*F1 + f0);
      den += (wA + wB) + (wC + wD);
      #pragma unroll
      for (int jj = 0; jj < 8; jj++){
        accA[jj] = fmaf(wA, bf2f((ush)vA[jj]), accA[jj]);
        accB[jj] = fmaf(wB, bf2f((ush)vB[jj]), accB[jj]);
        accA[jj] = fmaf(wC, bf2f((ush)vC[jj]), accA[jj]);
        accB[jj] = fmaf(wD, bf2f((ush)vD[jj]), accB[jj]);
      }
    }
    for (; j < cnt; j++){
      int sA = __shfl(myE, j, 64);
      float eA = als[sA*NH + h] + ad;
      eA = fmaxf(eA, 0.2f*eA);
      float wA = __expf(eA);
      short8 vA = *(const short8*)(xp1 + (size_t)sA*F1 + f0);
      den += wA;
      #pragma unroll
      for (int jj = 0; jj < 8; jj++)
        accA[jj] = fmaf(wA, bf2f((ush)vA[jj]), accA[jj]);
    }
  }
  float inv = 1.f / den;
  #pragma unroll
  for (int jj = 0; jj < 8; jj++){
    float o = (accA[jj] + accB[jj])*inv + b1[f0 + jj];
    o = o > 0.f ? o : expm1f(o);
    h1[(size_t)w*F1 + f0 + jj] = f2bf(o);
  }
}

// ---- layer-2 aggregation -> h2 bf16; 16-deep gather groups (8/4/1 fallback) ----
__global__ __launch_bounds__(256) void k_agg2(const int* __restrict__ offs,
                                              const int* __restrict__ esrc,
                                              const ush* __restrict__ xp2,
                                              const float* __restrict__ als,
                                              const float* __restrict__ ald,
                                              const float* __restrict__ b2,
                                              ush* __restrict__ h2g){
  int w = (blockIdx.x*256 + threadIdx.x) >> 6;
  int l = threadIdx.x & 63;
  if (w >= NN) return;
  float ad = ald[w];
  int s0 = offs[w], s1 = offs[w+1];
  float accA = 0.f, accB = 0.f, den = 0.f;

  for (int base = s0; base < s1; base += 64){
    int cnt = min(64, s1 - base);
    bool ok = (base + l < s1);
    int myE = ok ? esrc[base + l] : 0;
    float myW = 0.f;
    if (ok){
      float e_ = als[myE] + ad;
      e_ = fmaxf(e_, 0.2f*e_);
      myW = __expf(e_);
    }
    int j = 0;
    for (; j + 16 <= cnt; j += 16){
      int   sE[16];
      float wE[16], xE[16];
      #pragma unroll
      for (int q = 0; q < 16; q++){
        sE[q] = __shfl(myE, j+q, 64);
        wE[q] = __shfl(myW, j+q, 64);
      }
      #pragma unroll
      for (int q = 0; q < 16; q++)
        xE[q] = bf2f(xp2[(size_t)sE[q]*HID + l]);
      #pragma unroll
      for (int q = 0; q < 16; q += 2){
        den += wE[q] + wE[q+1];
        accA = fmaf(wE[q],   xE[q],   accA);
        accB = fmaf(wE[q+1], xE[q+1], accB);
      }
    }
    for (; j + 8 <= cnt; j += 8){
      int   sE[8];
      float wE[8], xE[8];
      #pragma unroll
      for (int q = 0; q < 8; q++){
        sE[q] = __shfl(myE, j+q, 64);
        wE[q] = __shfl(myW, j+q, 64);
      }
      #pragma unroll
      for (int q = 0; q < 8; q++)
        xE[q] = bf2f(xp2[(size_t)sE[q]*HID + l]);
      #pragma unroll
      for (int q = 0; q < 8; q += 2){
        den += wE[q] + wE[q+1];
        accA = fmaf(wE[q],   xE[q],   accA);
        accB = fmaf(wE[q+1], xE[q+1], accB);
      }
    }
    for (; j + 4 <= cnt; j += 4){
      int   sE[4];
      float wE[4], xE[4];
      #pragma unroll
      for (int q = 0; q < 4; q++){
        sE[q] = __shfl(myE, j+q, 64);
        wE[q] = __shfl(myW, j+q, 64);
      }
      #pragma unroll
      for (int q = 0; q < 4; q++)
        xE[q] = bf2f(xp2[(size_t)sE[q]*HID + l]);
      den += (wE[0] + wE[1]) + (wE[2] + wE[3]);
      accA = fmaf(wE[0], xE[0], accA); accB = fmaf(wE[1], xE[1], accB);
      accA = fmaf(wE[2], xE[2], accA); accB = fmaf(wE[3], xE[3], accB);
    }
    for (; j < cnt; j++){
      int sA = __shfl(myE, j, 64);
      float wA = __shfl(myW, j, 64);
      den += wA;
      accA = fmaf(wA, bf2f(xp2[(size_t)sA*HID + l]), accA);
    }
  }
  float h2 = (accA + accB) / den + b2[l];
  h2g[(size_t)w*HID + l] = f2bf(h2);
}

// ---- classifier MLP via MFMA ----
__global__ __launch_bounds__(256) void k_cls(const ush* __restrict__ h2g,
                                             const ush* __restrict__ Wc1t,
                                             const float* __restrict__ bc1,
                                             const float* __restrict__ Wc2,
                                             const float* __restrict__ bc2,
                                             float* __restrict__ out){
  const int t = threadIdx.x, wid = t>>6, l = t&63;
  const int lr = l&15, ksl = (l>>4)*8;
  const int m0 = blockIdx.x*128 + wid*32;

  f32x4 acc[2][4];
  #pragma unroll
  for (int m = 0; m < 2; m++)
    #pragma unroll
    for (int n = 0; n < 4; n++)
      #pragma unroll
      for (int j = 0; j < 4; j++) acc[m][n][j] = 0.f;

  #pragma unroll
  for (int ks = 0; ks < 2; ks++){
    short8 af[2], bfr[4];
    #pragma unroll
    for (int m = 0; m < 2; m++){
      int row = m0 + m*16 + lr;
      row = row < NN ? row : NN-1;
      af[m] = *(const short8*)(h2g + (size_t)row*HID + ks*32 + ksl);
    }
    #pragma unroll
    for (int n = 0; n < 4; n++)
      bfr[n] = *(const short8*)(Wc1t + (size_t)(n*16 + lr)*HID + ks*32 + ksl);
    #pragma unroll
    for (int m = 0; m < 2; m++)
      #pragma unroll
      for (int n = 0; n < 4; n++)
        acc[m][n] = __builtin_amdgcn_mfma_f32_16x16x32_bf16(af[m], bfr[n], acc[m][n], 0, 0, 0);
  }

  #pragma unroll
  for (int m = 0; m < 2; m++)
    #pragma unroll
    for (int j = 0; j < 4; j++){
      float q0 = 0.f, q1 = 0.f;
      #pragma unroll
      for (int n = 0; n < 4; n++){
        int col = n*16 + lr;
        float r = acc[m][n][j] + bc1[col];
        r = fmaxf(r, 0.f);
        q0 = fmaf(r, Wc2[col*2 + 0], q0);
        q1 = fmaf(r, Wc2[col*2 + 1], q1);
      }
      #pragma unroll
      for (int o = 1; o < 16; o <<= 1){
        q0 += __shfl_xor(q0, o, 64);
        q1 += __shfl_xor(q1, o, 64);
      }
      if (lr == 0){
        int row = m0 + m*16 + (l>>4)*4 + j;
        if (row < NN){
          out[(size_t)row*2 + 0] = q0 + bc2[0];
          out[(size_t)row*2 + 1] = q1 + bc2[1];
        }
      }
    }
}

extern "C" void kernel_launch(void* const* d_in, const int* in_sizes, int n_in,
                              void* d_out, int out_size, void* d_ws, size_t ws_size,
                              hipStream_t stream){
  const float* x   = (const float*)d_in[0];
  const int*   ei  = (const int*)  d_in[1];
  const float* W1  = (const float*)d_in[2];
  const float* as1 = (const float*)d_in[3];
  const float* ad1 = (const float*)d_in[4];
  const float* b1  = (const float*)d_in[5];
  const float* W2  = (const float*)d_in[6];
  const float* as2 = (const float*)d_in[7];
  const float* ad2 = (const float*)d_in[8];
  const float* b2  = (const float*)d_in[9];
  const float* Wc1 = (const float*)d_in[10];
  const float* bc1 = (const float*)d_in[11];
  const float* Wc2 = (const float*)d_in[12];
  const float* bc2 = (const float*)d_in[13];
  float* out = (float*)d_out;

  char* p = (char*)d_ws; size_t off = 0;
  auto alloc = [&](size_t b){ void* r = p + off; off = (off + b + 255) & ~(size_t)255; return r; };
  ush* xpad = (ush*)alloc((size_t)NN*KP1*2);
  ush* W1t  = (ush*)alloc((size_t)512*KP1*2);
  ush* W2t  = (ush*)alloc((size_t)HID*F1*2);
  ush* Wc1t = (ush*)alloc((size_t)HID*HID*2);
  ush* xp1  = (ush*)alloc((size_t)NN*F1*2);
  ush* h1   = (ush*)alloc((size_t)NN*F1*2);
  ush* xp2  = (ush*)alloc((size_t)NN*HID*2);
  ush* h2g  = (ush*)alloc((size_t)NN*HID*2);
  float* als1 = (float*)alloc((size_t)NN*NH*4);
  float* ald1 = (float*)alloc((size_t)NN*NH*4);
  float* als2 = (float*)alloc((size_t)NN*4);
  float* ald2 = (float*)alloc((size_t)NN*4);
  int* deg  = (int*)alloc((size_t)DEGPAD*4);
  int* cur  = (int*)alloc((size_t)NN*4);
  int* offs = (int*)alloc((size_t)(NN+1)*4);
  int* esrc = (int*)alloc((size_t)ET*4);

  hipMemsetAsync(deg, 0, (size_t)DEGPAD*4, stream);

  k_prep_v<<<(T3V + 255)/256, 256, 0, stream>>>(x, W1, W2, Wc1, ei, xpad, W1t, W2t, Wc1t, deg);
  k_scan<<<1, 1024, 0, stream>>>(deg, offs, cur);
  k_sg1<<<G1BLK + SCB, 256, 0, stream>>>(ei, offs, cur, esrc,
                                         xpad, W1t, as1, ad1, xp1, als1, ald1);
  // agg1 thirds: node-partitioned (proven ~free in r7); surfaces other kernels in top-5
  k_agg1<<<4167, 256, 0, stream>>>(offs, esrc, xp1, als1, ald1, b1, h1, 0,     16667);
  k_agg1<<<4167, 256, 0, stream>>>(offs, esrc, xp1, als1, ald1, b1, h1, 16667, 16667);
  k_agg1<<<4167, 256, 0, stream>>>(offs, esrc, xp1, als1, ald1, b1, h1, 33334, 16666);

  k_gemm2<<<391, 256, 0, stream>>>(h1, W2t, as2, ad2, xp2, als2, ald2);
  k_agg2<<<12500, 256, 0, stream>>>(offs, esrc, xp2, als2, ald2, b2, h2g);
  k_cls<<<391, 256, 0, stream>>>(h2g, Wc1t, bc1, Wc2, bc2, out);
}

// Round 15
// 361.097 us; speedup vs baseline: 1.1587x; 1.1587x over previous
//
#include <hip/hip_runtime.h>

#define NN   50000
#define E0   800000
#define ET   850000
#define FIN  166
#define KP1  192
#define HID  64
#define NH   8
#define F1   512
#define SCHUNK 52
#define DEGPAD (1024*SCHUNK)
#define G1BX 391
#define G1BLK (G1BX*4)
#define SCB  832

typedef __attribute__((ext_vector_type(8))) short short8;
typedef __attribute__((ext_vector_type(4))) float f32x4;
typedef __attribute__((ext_vector_type(4))) int int4v;
typedef unsigned short ush;

__device__ __forceinline__ float bf2f(unsigned short u){
  unsigned int x = ((unsigned int)u) << 16;
  return __builtin_bit_cast(float, x);
}
__device__ __forceinline__ unsigned short f2bf(float f){
  unsigned int x = __builtin_bit_cast(unsigned int, f);
  x += 0x7FFFu + ((x >> 16) & 1u);
  return (unsigned short)(x >> 16);
}

// ---- fused prep (8-wide): pad/convert x, transpose W1,W2,Wc1, histogram ----
#define G1 (KP1/8)
#define T0V (NN*G1)
#define T1V (T0V + 512*G1)
#define T2V (T1V + 64*64)
#define T2W (T2V + 512)
#define T3V (T2W + ET)
__global__ __launch_bounds__(256) void k_prep_v(const float* __restrict__ x,
                                                const float* __restrict__ W1,
                                                const float* __restrict__ W2,
                                                const float* __restrict__ Wc1,
                                                const int* __restrict__ ei,
                                                ush* __restrict__ xpad,
                                                ush* __restrict__ W1t,
                                                ush* __restrict__ W2t,
                                                ush* __restrict__ Wc1t,
                                                int* __restrict__ deg){
  int i = blockIdx.x*256 + threadIdx.x;
  if (i >= T3V) return;
  if (i < T0V){
    int n = i / G1, g = i - n*G1, k0 = g*8;
    short8 o;
    #pragma unroll
    for (int j = 0; j < 8; j++){
      int k = k0 + j;
      o[j] = (short)f2bf(k < FIN ? x[(size_t)n*FIN + k] : 0.f);
    }
    *(short8*)(xpad + (size_t)n*KP1 + k0) = o;
  } else if (i < T1V){
    int j = i - T0V;
    int col = j / G1, g = j - col*G1, k0 = g*8;
    short8 o;
    #pragma unroll
    for (int q = 0; q < 8; q++){
      int k = k0 + q;
      o[q] = (short)f2bf(k < FIN ? W1[(size_t)k*512 + col] : 0.f);
    }
    *(short8*)(W1t + (size_t)col*KP1 + k0) = o;
  } else if (i < T2V){
    int j = i - T1V;
    int col = j >> 6, g = j & 63, k0 = g*8;
    short8 o;
    #pragma unroll
    for (int q = 0; q < 8; q++)
      o[q] = (short)f2bf(W2[(size_t)(k0 + q)*HID + col]);
    *(short8*)(W2t + (size_t)col*F1 + k0) = o;
  } else if (i < T2W){
    int j = i - T2V;
    int col = j >> 3, k0 = (j & 7)*8;
    short8 o;
    #pragma unroll
    for (int q = 0; q < 8; q++)
      o[q] = (short)f2bf(Wc1[(size_t)(k0 + q)*HID + col]);
    *(short8*)(Wc1t + (size_t)col*HID + k0) = o;
  } else {
    int e = i - T2W;
    int dst = (e < E0) ? ei[E0 + e] : (e - E0);
    atomicAdd(&deg[dst], 1);
  }
}

// ---- exclusive scan of deg -> offs[NN+1]; also zeroes cur ----
__global__ __launch_bounds__(1024) void k_scan(const int* __restrict__ deg,
                                               int* __restrict__ offs,
                                               int* __restrict__ cur){
  __shared__ int sums[1024];
  int t = threadIdx.x;
  for (int i = t; i < NN; i += 1024) cur[i] = 0;
  int base = t * SCHUNK;
  int4v v[13];
  int loc = 0;
  #pragma unroll
  for (int c = 0; c < 13; c++){
    v[c] = *(const int4v*)(deg + base + c*4);
    loc += v[c].x + v[c].y + v[c].z + v[c].w;
  }
  sums[t] = loc; __syncthreads();
  for (int off = 1; off < 1024; off <<= 1){
    int s = (t >= off) ? sums[t - off] : 0;
    __syncthreads();
    sums[t] += s;
    __syncthreads();
  }
  int run = sums[t] - loc;
  #pragma unroll
  for (int c = 0; c < 13; c++){
    int i0 = base + c*4;
    if (i0 + 0 < NN) offs[i0 + 0] = run;  run += v[c].x;
    if (i0 + 1 < NN) offs[i0 + 1] = run;  run += v[c].y;
    if (i0 + 2 < NN) offs[i0 + 2] = run;  run += v[c].z;
    if (i0 + 3 < NN) offs[i0 + 3] = run;  run += v[c].w;
  }
  if (t == 1023) offs[NN] = sums[1023];
}

// ---- FUSED: scatter (last SCB blocks) + GEMM1 (first G1BLK blocks) ----
// GEMM1: B-panel in LDS once; A direct global; barrier-free K-loop;
// NEW: C written via LDS transpose -> fully coalesced full-line stores.
__global__ __launch_bounds__(256) void k_sg1(const int* __restrict__ ei,
                                             const int* __restrict__ offs,
                                             int* __restrict__ cur,
                                             int* __restrict__ esrc,
                                             const ush* __restrict__ xpad,
                                             const ush* __restrict__ W1t,
                                             const float* __restrict__ a_s,
                                             const float* __restrict__ a_d,
                                             ush* __restrict__ xp1,
                                             float* __restrict__ als,
                                             float* __restrict__ ald){
  __shared__ __align__(16) ush lds_u[128*200];   // 51.2 KB; Bs during K-loop, Cs after
  ush (*Bs)[200] = reinterpret_cast<ush(*)[200]>(lds_u);
  ush (*Cs)[136] = reinterpret_cast<ush(*)[136]>(lds_u);

  const int bid = blockIdx.x;
  if (bid >= G1BLK){
    int vb = bid - G1BLK;
    for (int e = vb*256 + (int)threadIdx.x; e < ET; e += SCB*256){
      int src, dst;
      if (e < E0){ src = ei[e]; dst = ei[E0 + e]; }
      else       { src = e - E0; dst = src; }
      int pos = offs[dst] + atomicAdd(&cur[dst], 1);
      esrc[pos] = src;
    }
    return;
  }
  const int m0 = (bid % G1BX)*128, n0 = (bid / G1BX)*128;
  const int t = threadIdx.x, wid = t>>6, l = t&63;
  const int wr = wid>>1, wc = wid&1;
  const int lr = l&15, ksl = (l>>4)*8;
  const int srow = t>>1, sc = (t&1)*16;

  // stage B-panel once: rows n0..n0+127, all 192 cols
  {
    const ush* Bp = W1t + (size_t)(n0 + srow)*KP1;
    #pragma unroll
    for (int c = 0; c < 6; c++){
      short8 b0 = *(const short8*)(Bp + c*32 + sc);
      short8 b1 = *(const short8*)(Bp + c*32 + sc + 8);
      *(short8*)&Bs[srow][c*32 + sc]     = b0;
      *(short8*)&Bs[srow][c*32 + sc + 8] = b1;
    }
  }
  __syncthreads();

  f32x4 acc[4][4];
  #pragma unroll
  for (int m = 0; m < 4; m++)
    #pragma unroll
    for (int n = 0; n < 4; n++)
      #pragma unroll
      for (int j = 0; j < 4; j++) acc[m][n][j] = 0.f;

  int arow[4];
  #pragma unroll
  for (int m = 0; m < 4; m++){
    int r = m0 + wr*64 + m*16 + lr;
    arow[m] = r < NN ? r : NN-1;     // clamp; OOB outputs guarded below
  }

  for (int s = 0; s < 6; s++){
    const int kk = s*32;
    short8 af[4], bfr[4];
    #pragma unroll
    for (int m = 0; m < 4; m++)
      af[m] = *(const short8*)(xpad + (size_t)arow[m]*KP1 + kk + ksl);
    #pragma unroll
    for (int n = 0; n < 4; n++)
      bfr[n] = *(const short8*)&Bs[wc*64 + n*16 + lr][kk + ksl];
    #pragma unroll
    for (int m = 0; m < 4; m++)
      #pragma unroll
      for (int n = 0; n < 4; n++)
        acc[m][n] = __builtin_amdgcn_mfma_f32_16x16x32_bf16(af[m], bfr[n], acc[m][n], 0, 0, 0);
  }

  // all waves done reading Bs before Cs overwrite
  __syncthreads();

  // scatter acc fragments into Cs (LDS), bf16
  #pragma unroll
  for (int m = 0; m < 4; m++)
    #pragma unroll
    for (int n = 0; n < 4; n++)
      #pragma unroll
      for (int j = 0; j < 4; j++){
        int rl = wr*64 + m*16 + (l>>4)*4 + j;
        int cl = wc*64 + n*16 + lr;
        Cs[rl][cl] = f2bf(acc[m][n][j]);
      }

  // fused attention-logit epilogue (registers only; overlaps LDS writes)
  const int head = (bid / G1BX)*2 + wc;
  float asv[4], adv[4];
  #pragma unroll
  for (int n = 0; n < 4; n++){
    asv[n] = a_s[head*64 + n*16 + lr];
    adv[n] = a_d[head*64 + n*16 + lr];
  }
  #pragma unroll
  for (int m = 0; m < 4; m++)
    #pragma unroll
    for (int j = 0; j < 4; j++){
      float ps = 0.f, pd = 0.f;
      #pragma unroll
      for (int n = 0; n < 4; n++){
        ps = fmaf(acc[m][n][j], asv[n], ps);
        pd = fmaf(acc[m][n][j], adv[n], pd);
      }
      #pragma unroll
      for (int o = 1; o < 16; o <<= 1){
        ps += __shfl_xor(ps, o, 64);
        pd += __shfl_xor(pd, o, 64);
      }
      if (lr == 0){
        int row = m0 + wr*64 + m*16 + (l>>4)*4 + j;
        if (row < NN){
          als[(size_t)row*NH + head] = fminf(fmaxf(ps, -30.f), 30.f);
          ald[(size_t)row*NH + head] = fminf(fmaxf(pd, -30.f), 30.f);
        }
      }
    }

  __syncthreads();

  // coalesced C store: flat short8 index f = k2*256 + t; 16 lanes = one full row
  #pragma unroll
  for (int k2 = 0; k2 < 8; k2++){
    int f = k2*256 + t;
    int row = f >> 4, ch = f & 15;
    int grow = m0 + row;
    if (grow < NN)
      *(short8*)(xp1 + (size_t)grow*F1 + n0 + ch*8) = *(const short8*)&Cs[row][ch*8];
  }
}

// ---- GEMM2: full-B in LDS once; A direct global; no k-loop barriers ----
__global__ __launch_bounds__(256) void k_gemm2(const ush* __restrict__ h1,
                                               const ush* __restrict__ W2t,
                                               const float* __restrict__ a_s,
                                               const float* __restrict__ a_d,
                                               ush* __restrict__ xp2,
                                               float* __restrict__ als,
                                               float* __restrict__ ald){
  __shared__ ush Bs[64][520];
  const int m0 = blockIdx.x*128;
  const int t = threadIdx.x, wid = t>>6, l = t&63;
  const int lr = l&15, ksl = (l>>4)*8;

  {
    const int br = t>>2, bq = (t&3)*128;
    const ush* Bp = W2t + (size_t)br*F1 + bq;
    #pragma unroll
    for (int c = 0; c < 16; c++){
      short8 b = *(const short8*)(Bp + c*8);
      *(short8*)&Bs[br][bq + c*8] = b;
    }
  }
  __syncthreads();

  f32x4 acc[2][4];
  #pragma unroll
  for (int m = 0; m < 2; m++)
    #pragma unroll
    for (int n = 0; n < 4; n++)
      #pragma unroll
      for (int j = 0; j < 4; j++) acc[m][n][j] = 0.f;

  int arow[2];
  #pragma unroll
  for (int m = 0; m < 2; m++){
    int r = m0 + wid*32 + m*16 + lr;
    arow[m] = r < NN ? r : NN-1;
  }

  for (int s = 0; s < 16; s++){
    const int kk = s*32;
    short8 af[2], bfr[4];
    #pragma unroll
    for (int m = 0; m < 2; m++)
      af[m] = *(const short8*)(h1 + (size_t)arow[m]*F1 + kk + ksl);
    #pragma unroll
    for (int n = 0; n < 4; n++)
      bfr[n] = *(const short8*)&Bs[n*16 + lr][kk + ksl];
    #pragma unroll
    for (int m = 0; m < 2; m++)
      #pragma unroll
      for (int n = 0; n < 4; n++)
        acc[m][n] = __builtin_amdgcn_mfma_f32_16x16x32_bf16(af[m], bfr[n], acc[m][n], 0, 0, 0);
  }

  #pragma unroll
  for (int m = 0; m < 2; m++)
    #pragma unroll
    for (int n = 0; n < 4; n++)
      #pragma unroll
      for (int j = 0; j < 4; j++){
        int row = m0 + wid*32 + m*16 + (l>>4)*4 + j;
        int col = n*16 + lr;
        if (row < NN) xp2[(size_t)row*HID + col] = f2bf(acc[m][n][j]);
      }

  float asv[4], adv[4];
  #pragma unroll
  for (int n = 0; n < 4; n++){
    asv[n] = a_s[n*16 + lr];
    adv[n] = a_d[n*16 + lr];
  }
  #pragma unroll
  for (int m = 0; m < 2; m++)
    #pragma unroll
    for (int j = 0; j < 4; j++){
      float ps = 0.f, pd = 0.f;
      #pragma unroll
      for (int n = 0; n < 4; n++){
        ps = fmaf(acc[m][n][j], asv[n], ps);
        pd = fmaf(acc[m][n][j], adv[n], pd);
      }
      #pragma unroll
      for (int o = 1; o < 16; o <<= 1){
        ps += __shfl_xor(ps, o, 64);
        pd += __shfl_xor(pd, o, 64);
      }
      if (lr == 0){
        int row = m0 + wid*32 + m*16 + (l>>4)*4 + j;
        if (row < NN){
          als[row] = fminf(fmaxf(ps, -30.f), 30.f);
          ald[row] = fminf(fmaxf(pd, -30.f), 30.f);
        }
      }
    }
}

// ---- layer-1 aggregation: wave per dst; chunked esrc via shfl; 4-way unroll ----
__global__ __launch_bounds__(256) void k_agg1(const int* __restrict__ offs,
                                              const int* __restrict__ esrc,
                                              const ush* __restrict__ xp1,
                                              const float* __restrict__ als,
                                              const float* __restrict__ ald,
                                              const float* __restrict__ b1,
                                              ush* __restrict__ h1){
  int w = (blockIdx.x*256 + threadIdx.x) >> 6;
  int l = threadIdx.x & 63;
  if (w >= NN) return;
  int h = l >> 3;
  int f0 = l * 8;
  float ad = ald[w*NH + h];
  int s0 = offs[w], s1 = offs[w+1];
  float accA[8], accB[8];
  #pragma unroll
  for (int j = 0; j < 8; j++){ accA[j] = 0.f; accB[j] = 0.f; }
  float den = 0.f;

  for (int base = s0; base < s1; base += 64){
    int cnt = min(64, s1 - base);
    int myE = (base + l < s1) ? esrc[base + l] : 0;
    int j = 0;
    for (; j + 4 <= cnt; j += 4){
      int sA = __shfl(myE, j,   64);
      int sB = __shfl(myE, j+1, 64);
      int sC = __shfl(myE, j+2, 64);
      int sD = __shfl(myE, j+3, 64);
      float eA = als[sA*NH + h] + ad;
      float eB = als[sB*NH + h] + ad;
      float eC = als[sC*NH + h] + ad;
      float eD = als[sD*NH + h] + ad;
      eA = fmaxf(eA, 0.2f*eA); eB = fmaxf(eB, 0.2f*eB);
      eC = fmaxf(eC, 0.2f*eC); eD = fmaxf(eD, 0.2f*eD);
      float wA = __expf(eA), wB = __expf(eB), wC = __expf(eC), wD = __expf(eD);
      short8 vA = *(const short8*)(xp1 + (size_t)sA*F1 + f0);
      short8 vB = *(const short8*)(xp1 + (size_t)sB*F1 + f0);
      short8 vC = *(const short8*)(xp1 + (size_t)sC*F1 + f0);
      short8 vD = *(const short8*)(xp1 + (size_t)sD*F1 + f0);
      den += (wA + wB) + (wC + wD);
      #pragma unroll
      for (int jj = 0; jj < 8; jj++){
        accA[jj] = fmaf(wA, bf2f((ush)vA[jj]), accA[jj]);
        accB[jj] = fmaf(wB, bf2f((ush)vB[jj]), accB[jj]);
        accA[jj] = fmaf(wC, bf2f((ush)vC[jj]), accA[jj]);
        accB[jj] = fmaf(wD, bf2f((ush)vD[jj]), accB[jj]);
      }
    }
    for (; j < cnt; j++){
      int sA = __shfl(myE, j, 64);
      float eA = als[sA*NH + h] + ad;
      eA = fmaxf(eA, 0.2f*eA);
      float wA = __expf(eA);
      short8 vA = *(const short8*)(xp1 + (size_t)sA*F1 + f0);
      den += wA;
      #pragma unroll
      for (int jj = 0; jj < 8; jj++)
        accA[jj] = fmaf(wA, bf2f((ush)vA[jj]), accA[jj]);
    }
  }
  float inv = 1.f / den;
  #pragma unroll
  for (int jj = 0; jj < 8; jj++){
    float o = (accA[jj] + accB[jj])*inv + b1[f0 + jj];
    o = o > 0.f ? o : expm1f(o);
    h1[(size_t)w*F1 + f0 + jj] = f2bf(o);
  }
}

// ---- layer-2 aggregation -> h2 bf16 (8-deep, in-wave weights) ----
__global__ __launch_bounds__(256) void k_agg2(const int* __restrict__ offs,
                                              const int* __restrict__ esrc,
                                              const ush* __restrict__ xp2,
                                              const float* __restrict__ als,
                                              const float* __restrict__ ald,
                                              const float* __restrict__ b2,
                                              ush* __restrict__ h2g){
  int w = (blockIdx.x*256 + threadIdx.x) >> 6;
  int l = threadIdx.x & 63;
  if (w >= NN) return;
  float ad = ald[w];
  int s0 = offs[w], s1 = offs[w+1];
  float accA = 0.f, accB = 0.f, den = 0.f;

  for (int base = s0; base < s1; base += 64){
    int cnt = min(64, s1 - base);
    bool ok = (base + l < s1);
    int myE = ok ? esrc[base + l] : 0;
    float myW = 0.f;
    if (ok){
      float e_ = als[myE] + ad;
      e_ = fmaxf(e_, 0.2f*e_);
      myW = __expf(e_);
    }
    int j = 0;
    for (; j + 8 <= cnt; j += 8){
      int sA = __shfl(myE, j,   64), sB = __shfl(myE, j+1, 64);
      int sC = __shfl(myE, j+2, 64), sD = __shfl(myE, j+3, 64);
      int sE = __shfl(myE, j+4, 64), sF = __shfl(myE, j+5, 64);
      int sG = __shfl(myE, j+6, 64), sH = __shfl(myE, j+7, 64);
      float wA = __shfl(myW, j,   64), wB = __shfl(myW, j+1, 64);
      float wC = __shfl(myW, j+2, 64), wD = __shfl(myW, j+3, 64);
      float wE = __shfl(myW, j+4, 64), wF = __shfl(myW, j+5, 64);
      float wG = __shfl(myW, j+6, 64), wH = __shfl(myW, j+7, 64);
      float xA = bf2f(xp2[(size_t)sA*HID + l]);
      float xB = bf2f(xp2[(size_t)sB*HID + l]);
      float xC = bf2f(xp2[(size_t)sC*HID + l]);
      float xD = bf2f(xp2[(size_t)sD*HID + l]);
      float xE = bf2f(xp2[(size_t)sE*HID + l]);
      float xF = bf2f(xp2[(size_t)sF*HID + l]);
      float xG = bf2f(xp2[(size_t)sG*HID + l]);
      float xH = bf2f(xp2[(size_t)sH*HID + l]);
      den += ((wA + wB) + (wC + wD)) + ((wE + wF) + (wG + wH));
      accA = fmaf(wA, xA, accA); accB = fmaf(wB, xB, accB);
      accA = fmaf(wC, xC, accA); accB = fmaf(wD, xD, accB);
      accA = fmaf(wE, xE, accA); accB = fmaf(wF, xF, accB);
      accA = fmaf(wG, xG, accA); accB = fmaf(wH, xH, accB);
    }
    for (; j < cnt; j++){
      int sA = __shfl(myE, j, 64);
      float wA = __shfl(myW, j, 64);
      den += wA;
      accA = fmaf(wA, bf2f(xp2[(size_t)sA*HID + l]), accA);
    }
  }
  float h2 = (accA + accB) / den + b2[l];
  h2g[(size_t)w*HID + l] = f2bf(h2);
}

// ---- classifier MLP via MFMA ----
__global__ __launch_bounds__(256) void k_cls(const ush* __restrict__ h2g,
                                             const ush* __restrict__ Wc1t,
                                             const float* __restrict__ bc1,
                                             const float* __restrict__ Wc2,
                                             const float* __restrict__ bc2,
                                             float* __restrict__ out){
  const int t = threadIdx.x, wid = t>>6, l = t&63;
  const int lr = l&15, ksl = (l>>4)*8;
  const int m0 = blockIdx.x*128 + wid*32;

  f32x4 acc[2][4];
  #pragma unroll
  for (int m = 0; m < 2; m++)
    #pragma unroll
    for (int n = 0; n < 4; n++)
      #pragma unroll
      for (int j = 0; j < 4; j++) acc[m][n][j] = 0.f;

  #pragma unroll
  for (int ks = 0; ks < 2; ks++){
    short8 af[2], bfr[4];
    #pragma unroll
    for (int m = 0; m < 2; m++){
      int row = m0 + m*16 + lr;
      row = row < NN ? row : NN-1;
      af[m] = *(const short8*)(h2g + (size_t)row*HID + ks*32 + ksl);
    }
    #pragma unroll
    for (int n = 0; n < 4; n++)
      bfr[n] = *(const short8*)(Wc1t + (size_t)(n*16 + lr)*HID + ks*32 + ksl);
    #pragma unroll
    for (int m = 0; m < 2; m++)
      #pragma unroll
      for (int n = 0; n < 4; n++)
        acc[m][n] = __builtin_amdgcn_mfma_f32_16x16x32_bf16(af[m], bfr[n], acc[m][n], 0, 0, 0);
  }

  #pragma unroll
  for (int m = 0; m < 2; m++)
    #pragma unroll
    for (int j = 0; j < 4; j++){
      float q0 = 0.f, q1 = 0.f;
      #pragma unroll
      for (int n = 0; n < 4; n++){
        int col = n*16 + lr;
        float r = acc[m][n][j] + bc1[col];
        r = fmaxf(r, 0.f);
        q0 = fmaf(r, Wc2[col*2 + 0], q0);
        q1 = fmaf(r, Wc2[col*2 + 1], q1);
      }
      #pragma unroll
      for (int o = 1; o < 16; o <<= 1){
        q0 += __shfl_xor(q0, o, 64);
        q1 += __shfl_xor(q1, o, 64);
      }
      if (lr == 0){
        int row = m0 + m*16 + (l>>4)*4 + j;
        if (row < NN){
          out[(size_t)row*2 + 0] = q0 + bc2[0];
          out[(size_t)row*2 + 1] = q1 + bc2[1];
        }
      }
    }
}

extern "C" void kernel_launch(void* const* d_in, const int* in_sizes, int n_in,
                              void* d_out, int out_size, void* d_ws, size_t ws_size,
                              hipStream_t stream){
  const float* x   = (const float*)d_in[0];
  const int*   ei  = (const int*)  d_in[1];
  const float* W1  = (const float*)d_in[2];
  const float* as1 = (const float*)d_in[3];
  const float* ad1 = (const float*)d_in[4];
  const float* b1  = (const float*)d_in[5];
  const float* W2  = (const float*)d_in[6];
  const float* as2 = (const float*)d_in[7];
  const float* ad2 = (const float*)d_in[8];
  const float* b2  = (const float*)d_in[9];
  const float* Wc1 = (const float*)d_in[10];
  const float* bc1 = (const float*)d_in[11];
  const float* Wc2 = (const float*)d_in[12];
  const float* bc2 = (const float*)d_in[13];
  float* out = (float*)d_out;

  char* p = (char*)d_ws; size_t off = 0;
  auto alloc = [&](size_t b){ void* r = p + off; off = (off + b + 255) & ~(size_t)255; return r; };
  ush* xpad = (ush*)alloc((size_t)NN*KP1*2);
  ush* W1t  = (ush*)alloc((size_t)512*KP1*2);
  ush* W2t  = (ush*)alloc((size_t)HID*F1*2);
  ush* Wc1t = (ush*)alloc((size_t)HID*HID*2);
  ush* xp1  = (ush*)alloc((size_t)NN*F1*2);
  ush* h1   = (ush*)alloc((size_t)NN*F1*2);
  ush* xp2  = (ush*)alloc((size_t)NN*HID*2);
  ush* h2g  = (ush*)alloc((size_t)NN*HID*2);
  float* als1 = (float*)alloc((size_t)NN*NH*4);
  float* ald1 = (float*)alloc((size_t)NN*NH*4);
  float* als2 = (float*)alloc((size_t)NN*4);
  float* ald2 = (float*)alloc((size_t)NN*4);
  int* deg  = (int*)alloc((size_t)DEGPAD*4);
  int* cur  = (int*)alloc((size_t)NN*4);
  int* offs = (int*)alloc((size_t)(NN+1)*4);
  int* esrc = (int*)alloc((size_t)ET*4);

  hipMemsetAsync(deg, 0, (size_t)DEGPAD*4, stream);

  k_prep_v<<<(T3V + 255)/256, 256, 0, stream>>>(x, W1, W2, Wc1, ei, xpad, W1t, W2t, Wc1t, deg);
  k_scan<<<1, 1024, 0, stream>>>(deg, offs, cur);
  k_sg1<<<G1BLK + SCB, 256, 0, stream>>>(ei, offs, cur, esrc,
                                         xpad, W1t, as1, ad1, xp1, als1, ald1);
  k_agg1<<<12500, 256, 0, stream>>>(offs, esrc, xp1, als1, ald1, b1, h1);

  k_gemm2<<<391, 256, 0, stream>>>(h1, W2t, as2, ad2, xp2, als2, ald2);
  k_agg2<<<12500, 256, 0, stream>>>(offs, esrc, xp2, als2, ald2, b2, h2g);
  k_cls<<<391, 256, 0, stream>>>(h2g, Wc1t, bc1, Wc2, bc2, out);
}